// Round 4
// baseline (352.365 us; speedup 1.0000x reference)
//
#include <hip/hip_runtime.h>
#include <math.h>

#define NUM_CLASSES 80
#define MT 50              // max targets per image
#define ATOT 8400          // 80*80 + 40*40 + 20*20
#define CH 85              // 5 + NUM_CLASSES
#define EPI (ATOT * CH)    // 714000 floats per image
#define BLOCK 256
#define CHUNK 256          // anchors per block
#define NBY 33             // ceil(ATOT / CHUNK)
#define NWAVE (BLOCK / 64)
#define ILP 8

__device__ __forceinline__ float softplus_fast(float x) {
    // stable softplus via HW transcendentals: max(x,0) + log(1 + exp(-|x|))
    return fmaxf(x, 0.0f) + __logf(1.0f + __expf(-fabsf(x)));
}

// ---------------- Fused kernel: match + IoU + obj + compacted cls ----------
// One block owns 256 consecutive anchors of one image.
// Phase 1 (anchor-per-thread): nearest-target match (targets compacted in
//   LDS), obj BCE for ALL anchors, box IoU for positives. Positives are
//   ballot-compacted into an LDS list.
// Phase 2: dense class sweep over npos*80 elements from the compacted list —
//   no dead iterations, coalesced scalar loads, 8-deep ILP.
// Tail: last-block-done ticket (device-scope atomic + fences) performs the
//   per-image normalize + global reduce in-kernel — no second launch.
__global__ __launch_bounds__(BLOCK) void yolox_fused(
        const float* __restrict__ pred,   // [B, ATOT, CH]
        const float* __restrict__ tgt,    // [B, MT, 5]
        const int*   __restrict__ isz,
        float* __restrict__ acc,          // [B, NBY, 4]  box, np, obj, cls
        unsigned* __restrict__ ticket,    // [1], pre-zeroed
        float* __restrict__ out,
        int B, int nblocks) {
    const int b  = blockIdx.y;
    const int by = blockIdx.x;
    const int a0 = by * CHUNK;
    const int nanch = min(CHUNK, ATOT - a0);
    const int tid = threadIdx.x;

    __shared__ float2 sxy[64];
    __shared__ float2 swh[64];
    __shared__ float  scls[64];
    __shared__ int    snv;
    __shared__ int    swcnt[NWAVE];       // per-wave positive counts
    __shared__ int    splist[CHUNK];      // (cls<<8)|a_local for positives

    // wave-0 ballot compaction of valid targets (order-preserving)
    if (tid < 64) {
        const int m = tid;
        const float fsize = (float)(*isz);
        float c = -1.0f, x = 0.f, y = 0.f, w = 0.f, h = 0.f;
        if (m < MT) {
            const float* tb = tgt + (size_t)b * MT * 5 + (size_t)m * 5;
            c = tb[0];
            x = tb[1] * fsize; y = tb[2] * fsize;
            w = tb[3] * fsize; h = tb[4] * fsize;
        }
        const bool valid = (m < MT) && (c >= 0.0f);
        const unsigned long long ballot = __ballot(valid);
        const int slot = __popcll(ballot & ((1ull << tid) - 1ull));
        if (valid) {
            sxy[slot]  = make_float2(x, y);
            swh[slot]  = make_float2(w, h);
            scls[slot] = c;
        }
        if (m == 0) snv = (int)__popcll(ballot);
    }
    __syncthreads();
    const int nv = snv;

    const float* pblock = pred + (size_t)b * EPI + (size_t)a0 * CH;

    float box_s = 0.f, np_s = 0.f, obj_s = 0.f;
    int myCls = -1;

    if (tid < nanch) {
        const int a = a0 + tid;
        // anchor geometry, compile-time divisors (magic-mul)
        float ax, ay;
        if (a < 6400)      { const int yy = a / 80;              const int xx = a - yy * 80;  ax = (float)(xx * 8  + 4);  ay = (float)(yy * 8  + 4); }
        else if (a < 8000) { const int i2 = a - 6400; const int yy = i2 / 40; const int xx = i2 - yy * 40; ax = (float)(xx * 16 + 8);  ay = (float)(yy * 16 + 8); }
        else               { const int i2 = a - 8000; const int yy = i2 / 20; const int xx = i2 - yy * 20; ax = (float)(xx * 32 + 16); ay = (float)(yy * 32 + 16); }

        float best = INFINITY;
        int bestm = 0;
        for (int m = 0; m < nv; ++m) {
            const float2 g = sxy[m];
            const float dx = g.x - ax, dy = g.y - ay;
            const float d2 = dx * dx + dy * dy;
            if (d2 < best) { best = d2; bestm = m; }
        }
        const bool pos = best < 4096.0f;  // 64^2

        const float* p = pblock + tid * CH;
        // obj BCE for every anchor: softplus(x) - t*x, t = pos
        const float xo = p[4];
        obj_s = softplus_fast(xo) - (pos ? xo : 0.0f);

        if (pos) {
            myCls = (int)scls[bestm];
            np_s  = 1.0f;
            const float pcx = p[0], pcy = p[1];
            const float pw = __expf(p[2]), ph = __expf(p[3]);
            const float2 g  = sxy[bestm];
            const float2 wh = swh[bestm];
            const float p1x = pcx - pw * 0.5f, p2x = pcx + pw * 0.5f;
            const float p1y = pcy - ph * 0.5f, p2y = pcy + ph * 0.5f;
            const float t1x = g.x - wh.x * 0.5f, t2x = g.x + wh.x * 0.5f;
            const float t1y = g.y - wh.y * 0.5f, t2y = g.y + wh.y * 0.5f;
            const float iw = fminf(p2x, t2x) - fmaxf(p1x, t1x);
            const float ih = fminf(p2y, t2y) - fmaxf(p1y, t1y);
            const float inter = fmaxf(iw, 0.f) * fmaxf(ih, 0.f);
            const float pa = (p2x - p1x) * (p2y - p1y);
            const float ta = (t2x - t1x) * (t2y - t1y);
            const float uni = pa + ta - inter;
            box_s = 1.0f - inter / (uni + 1e-6f);
        }
    }

    // ---------------- block-wide compaction of positive anchors ------------
    const bool isPos = (myCls >= 0);
    const unsigned long long bal = __ballot(isPos);
    const int wave = tid >> 6;
    const int lane = tid & 63;
    if (lane == 0) swcnt[wave] = (int)__popcll(bal);
    __syncthreads();
    int woff = 0, npos = 0;
    #pragma unroll
    for (int w = 0; w < NWAVE; ++w) {
        const int c = swcnt[w];
        if (w < wave) woff += c;
        npos += c;
    }
    if (isPos) {
        const int slot = woff + (int)__popcll(bal & ((1ull << lane) - 1ull));
        splist[slot] = (myCls << 8) | tid;
    }
    __syncthreads();

    // ---------------- Phase 2: dense class sweep over positives ------------
    float cls_s = 0.f;
    const int total = npos * NUM_CLASSES;

    int i = tid;
    for (; i + (ILP - 1) * BLOCK < total; i += ILP * BLOCK) {
        int   off[ILP], cc[ILP], mm[ILP];
        #pragma unroll
        for (int k = 0; k < ILP; ++k) {
            const unsigned ii = (unsigned)(i + k * BLOCK);
            const unsigned pi = ii / NUM_CLASSES;          // compile-time magic
            const int c  = (int)(ii - pi * NUM_CLASSES);
            const int pk = splist[pi];
            const int a  = pk & 0xFF;
            cc[k]  = c;
            mm[k]  = pk >> 8;
            off[k] = a * CH + 5 + c;
        }
        float x[ILP];
        #pragma unroll
        for (int k = 0; k < ILP; ++k) x[k] = pblock[off[k]];
        #pragma unroll
        for (int k = 0; k < ILP; ++k)
            cls_s += softplus_fast(x[k]) - ((cc[k] == mm[k]) ? x[k] : 0.0f);
    }
    for (; i < total; i += BLOCK) {
        const unsigned ii = (unsigned)i;
        const unsigned pi = ii / NUM_CLASSES;
        const int c  = (int)(ii - pi * NUM_CLASSES);
        const int pk = splist[pi];
        const int a  = pk & 0xFF;
        const int m  = pk >> 8;
        const float x = pblock[a * CH + 5 + c];
        cls_s += softplus_fast(x) - ((c == m) ? x : 0.0f);
    }

    // ---------------- block reduction of (box, np, obj, cls) ---------------
    float v0 = box_s, v1 = np_s, v2 = obj_s, v3 = cls_s;
    for (int off2 = 32; off2 > 0; off2 >>= 1) {
        v0 += __shfl_down(v0, off2, 64);
        v1 += __shfl_down(v1, off2, 64);
        v2 += __shfl_down(v2, off2, 64);
        v3 += __shfl_down(v3, off2, 64);
    }
    __shared__ float sred[NWAVE][4];
    if (lane == 0) {
        sred[wave][0] = v0; sred[wave][1] = v1;
        sred[wave][2] = v2; sred[wave][3] = v3;
    }
    __syncthreads();

    __shared__ int sIsLast;
    if (tid == 0) {
        float t0 = 0.f, t1 = 0.f, t2 = 0.f, t3 = 0.f;
        #pragma unroll
        for (int w = 0; w < NWAVE; ++w) {
            t0 += sred[w][0]; t1 += sred[w][1];
            t2 += sred[w][2]; t3 += sred[w][3];
        }
        float* slot = acc + ((size_t)b * NBY + by) * 4;
        slot[0] = t0; slot[1] = t1; slot[2] = t2; slot[3] = t3;
        __threadfence();                        // publish acc slot (device scope)
        const unsigned prev = atomicAdd(ticket, 1u);
        sIsLast = (prev == (unsigned)(nblocks - 1)) ? 1 : 0;
    }
    __syncthreads();
    if (sIsLast == 0) return;

    // ---------------- last block: per-image normalize + final reduce -------
    __threadfence();                            // acquire all acc slots

    float obj = 0.f, cls = 0.f, box = 0.f, np = 0.f;
    for (int bb = tid; bb < B; bb += BLOCK) {
        float bs = 0.f, ps = 0.f, os = 0.f, cs = 0.f;
        const float* s = acc + (size_t)bb * NBY * 4;
        #pragma unroll
        for (int j = 0; j < NBY; ++j) {
            bs += s[j * 4 + 0]; ps += s[j * 4 + 1];
            os += s[j * 4 + 2]; cs += s[j * 4 + 3];
        }
        obj += os * (1.0f / (float)ATOT);
        const float denom = fmaxf(ps, 1.0f);
        cls += (ps > 0.f) ? cs / (denom * (float)NUM_CLASSES) : 0.f;
        box += (ps > 0.f) ? bs / denom : 0.f;
        np  += ps;
    }
    float u0 = obj, u1 = cls, u2 = box, u3 = np;
    for (int off = 32; off > 0; off >>= 1) {
        u0 += __shfl_down(u0, off, 64);
        u1 += __shfl_down(u1, off, 64);
        u2 += __shfl_down(u2, off, 64);
        u3 += __shfl_down(u3, off, 64);
    }
    __shared__ float sfin[NWAVE][4];
    if (lane == 0) {
        sfin[wave][0] = u0; sfin[wave][1] = u1;
        sfin[wave][2] = u2; sfin[wave][3] = u3;
    }
    __syncthreads();
    if (tid == 0) {
        float t0 = 0.f, t1 = 0.f, t2 = 0.f, t3 = 0.f;
        #pragma unroll
        for (int w = 0; w < NWAVE; ++w) {
            t0 += sfin[w][0]; t1 += sfin[w][1];
            t2 += sfin[w][2]; t3 += sfin[w][3];
        }
        out[0] = 5.0f * t2 + t0 + t1;  // total
        out[1] = t2;
        out[2] = t0;
        out[3] = t1;
        out[4] = t3;
    }
}

extern "C" void kernel_launch(void* const* d_in, const int* in_sizes, int n_in,
                              void* d_out, int out_size, void* d_ws, size_t ws_size,
                              hipStream_t stream) {
    const float* pred = (const float*)d_in[0];
    const float* tgt  = (const float*)d_in[1];
    const int*   isz  = (const int*)d_in[2];
    float* out = (float*)d_out;

    const int B = in_sizes[1] / (MT * 5);

    // ws layout: acc [B*NBY*4] floats, then ticket [1] unsigned
    float*    acc    = (float*)d_ws;
    unsigned* ticket = (unsigned*)(acc + (size_t)B * NBY * 4);

    hipMemsetAsync(ticket, 0, sizeof(unsigned), stream);

    dim3 grid(NBY, B);
    yolox_fused<<<grid, BLOCK, 0, stream>>>(pred, tgt, isz, acc, ticket, out,
                                            B, NBY * B);
}

// Round 5
// 268.581 us; speedup vs baseline: 1.3120x; 1.3120x over previous
//
#include <hip/hip_runtime.h>
#include <math.h>

#define NUM_CLASSES 80
#define MT 50              // max targets per image
#define ATOT 8400          // 80*80 + 40*40 + 20*20
#define CH 85              // 5 + NUM_CLASSES
#define EPI (ATOT * CH)    // 714000 floats per image
#define BLOCK 256
#define CHUNK 256          // anchors per block
#define NBY 33             // ceil(ATOT / CHUNK)
#define NWAVE (BLOCK / 64)
#define ILP 8

__device__ __forceinline__ float softplus_fast(float x) {
    // stable softplus via HW transcendentals: max(x,0) + log(1 + exp(-|x|))
    return fmaxf(x, 0.0f) + __logf(1.0f + __expf(-fabsf(x)));
}

// ---------------- Fused kernel: match + IoU + obj + compacted cls ----------
// One block owns 256 consecutive anchors of one image.
// Phase 1 (anchor-per-thread): nearest-target match (targets compacted in
//   LDS), obj BCE for ALL anchors, box IoU for positives. Positives are
//   ballot-compacted into an LDS list.
// Phase 2: dense class sweep over npos*80 elements from the compacted list.
// Tail: last-block-done ticket performs the per-image normalize + global
//   reduce in-kernel. Coherence via AGENT-scope relaxed atomics on the 4
//   partials only (sc-bit stores/loads reach the device coherence point) —
//   NOT __threadfence(), whose buffer_wbl2/buffer_inv per block (2112 L2
//   flushes) caused the R4 166 µs regression.
__global__ __launch_bounds__(BLOCK) void yolox_fused(
        const float* __restrict__ pred,   // [B, ATOT, CH]
        const float* __restrict__ tgt,    // [B, MT, 5]
        const int*   __restrict__ isz,
        float* __restrict__ acc,          // [B, NBY, 4]  box, np, obj, cls
        unsigned* __restrict__ ticket,    // [1], pre-zeroed
        float* __restrict__ out,
        int B, int nblocks) {
    const int b  = blockIdx.y;
    const int by = blockIdx.x;
    const int a0 = by * CHUNK;
    const int nanch = min(CHUNK, ATOT - a0);
    const int tid = threadIdx.x;

    __shared__ float2 sxy[64];
    __shared__ float2 swh[64];
    __shared__ float  scls[64];
    __shared__ int    snv;
    __shared__ int    swcnt[NWAVE];       // per-wave positive counts
    __shared__ int    splist[CHUNK];      // (cls<<8)|a_local for positives

    // wave-0 ballot compaction of valid targets (order-preserving)
    if (tid < 64) {
        const int m = tid;
        const float fsize = (float)(*isz);
        float c = -1.0f, x = 0.f, y = 0.f, w = 0.f, h = 0.f;
        if (m < MT) {
            const float* tb = tgt + (size_t)b * MT * 5 + (size_t)m * 5;
            c = tb[0];
            x = tb[1] * fsize; y = tb[2] * fsize;
            w = tb[3] * fsize; h = tb[4] * fsize;
        }
        const bool valid = (m < MT) && (c >= 0.0f);
        const unsigned long long ballot = __ballot(valid);
        const int slot = __popcll(ballot & ((1ull << tid) - 1ull));
        if (valid) {
            sxy[slot]  = make_float2(x, y);
            swh[slot]  = make_float2(w, h);
            scls[slot] = c;
        }
        if (m == 0) snv = (int)__popcll(ballot);
    }
    __syncthreads();
    const int nv = snv;

    const float* pblock = pred + (size_t)b * EPI + (size_t)a0 * CH;

    float box_s = 0.f, np_s = 0.f, obj_s = 0.f;
    int myCls = -1;

    if (tid < nanch) {
        const int a = a0 + tid;
        // anchor geometry, compile-time divisors (magic-mul)
        float ax, ay;
        if (a < 6400)      { const int yy = a / 80;              const int xx = a - yy * 80;  ax = (float)(xx * 8  + 4);  ay = (float)(yy * 8  + 4); }
        else if (a < 8000) { const int i2 = a - 6400; const int yy = i2 / 40; const int xx = i2 - yy * 40; ax = (float)(xx * 16 + 8);  ay = (float)(yy * 16 + 8); }
        else               { const int i2 = a - 8000; const int yy = i2 / 20; const int xx = i2 - yy * 20; ax = (float)(xx * 32 + 16); ay = (float)(yy * 32 + 16); }

        float best = INFINITY;
        int bestm = 0;
        for (int m = 0; m < nv; ++m) {
            const float2 g = sxy[m];
            const float dx = g.x - ax, dy = g.y - ay;
            const float d2 = dx * dx + dy * dy;
            if (d2 < best) { best = d2; bestm = m; }
        }
        const bool pos = best < 4096.0f;  // 64^2

        const float* p = pblock + tid * CH;
        // obj BCE for every anchor: softplus(x) - t*x, t = pos
        const float xo = p[4];
        obj_s = softplus_fast(xo) - (pos ? xo : 0.0f);

        if (pos) {
            myCls = (int)scls[bestm];
            np_s  = 1.0f;
            const float pcx = p[0], pcy = p[1];
            const float pw = __expf(p[2]), ph = __expf(p[3]);
            const float2 g  = sxy[bestm];
            const float2 wh = swh[bestm];
            const float p1x = pcx - pw * 0.5f, p2x = pcx + pw * 0.5f;
            const float p1y = pcy - ph * 0.5f, p2y = pcy + ph * 0.5f;
            const float t1x = g.x - wh.x * 0.5f, t2x = g.x + wh.x * 0.5f;
            const float t1y = g.y - wh.y * 0.5f, t2y = g.y + wh.y * 0.5f;
            const float iw = fminf(p2x, t2x) - fmaxf(p1x, t1x);
            const float ih = fminf(p2y, t2y) - fmaxf(p1y, t1y);
            const float inter = fmaxf(iw, 0.f) * fmaxf(ih, 0.f);
            const float pa = (p2x - p1x) * (p2y - p1y);
            const float ta = (t2x - t1x) * (t2y - t1y);
            const float uni = pa + ta - inter;
            box_s = 1.0f - inter / (uni + 1e-6f);
        }
    }

    // ---------------- block-wide compaction of positive anchors ------------
    const bool isPos = (myCls >= 0);
    const unsigned long long bal = __ballot(isPos);
    const int wave = tid >> 6;
    const int lane = tid & 63;
    if (lane == 0) swcnt[wave] = (int)__popcll(bal);
    __syncthreads();
    int woff = 0, npos = 0;
    #pragma unroll
    for (int w = 0; w < NWAVE; ++w) {
        const int c = swcnt[w];
        if (w < wave) woff += c;
        npos += c;
    }
    if (isPos) {
        const int slot = woff + (int)__popcll(bal & ((1ull << lane) - 1ull));
        splist[slot] = (myCls << 8) | tid;
    }
    __syncthreads();

    // ---------------- Phase 2: dense class sweep over positives ------------
    float cls_s = 0.f;
    const int total = npos * NUM_CLASSES;

    int i = tid;
    for (; i + (ILP - 1) * BLOCK < total; i += ILP * BLOCK) {
        int   off[ILP], cc[ILP], mm[ILP];
        #pragma unroll
        for (int k = 0; k < ILP; ++k) {
            const unsigned ii = (unsigned)(i + k * BLOCK);
            const unsigned pi = ii / NUM_CLASSES;          // compile-time magic
            const int c  = (int)(ii - pi * NUM_CLASSES);
            const int pk = splist[pi];
            const int a  = pk & 0xFF;
            cc[k]  = c;
            mm[k]  = pk >> 8;
            off[k] = a * CH + 5 + c;
        }
        float x[ILP];
        #pragma unroll
        for (int k = 0; k < ILP; ++k) x[k] = pblock[off[k]];
        #pragma unroll
        for (int k = 0; k < ILP; ++k)
            cls_s += softplus_fast(x[k]) - ((cc[k] == mm[k]) ? x[k] : 0.0f);
    }
    for (; i < total; i += BLOCK) {
        const unsigned ii = (unsigned)i;
        const unsigned pi = ii / NUM_CLASSES;
        const int c  = (int)(ii - pi * NUM_CLASSES);
        const int pk = splist[pi];
        const int a  = pk & 0xFF;
        const int m  = pk >> 8;
        const float x = pblock[a * CH + 5 + c];
        cls_s += softplus_fast(x) - ((c == m) ? x : 0.0f);
    }

    // ---------------- block reduction of (box, np, obj, cls) ---------------
    float v0 = box_s, v1 = np_s, v2 = obj_s, v3 = cls_s;
    for (int off2 = 32; off2 > 0; off2 >>= 1) {
        v0 += __shfl_down(v0, off2, 64);
        v1 += __shfl_down(v1, off2, 64);
        v2 += __shfl_down(v2, off2, 64);
        v3 += __shfl_down(v3, off2, 64);
    }
    __shared__ float sred[NWAVE][4];
    if (lane == 0) {
        sred[wave][0] = v0; sred[wave][1] = v1;
        sred[wave][2] = v2; sred[wave][3] = v3;
    }
    __syncthreads();

    __shared__ int sIsLast;
    if (tid == 0) {
        float t0 = 0.f, t1 = 0.f, t2 = 0.f, t3 = 0.f;
        #pragma unroll
        for (int w = 0; w < NWAVE; ++w) {
            t0 += sred[w][0]; t1 += sred[w][1];
            t2 += sred[w][2]; t3 += sred[w][3];
        }
        float* slot = acc + ((size_t)b * NBY + by) * 4;
        // device-coherent partial publish: sc-bit stores reach the coherence
        // point directly; no L2 writeback/invalidate.
        __hip_atomic_store(&slot[0], t0, __ATOMIC_RELAXED, __HIP_MEMORY_SCOPE_AGENT);
        __hip_atomic_store(&slot[1], t1, __ATOMIC_RELAXED, __HIP_MEMORY_SCOPE_AGENT);
        __hip_atomic_store(&slot[2], t2, __ATOMIC_RELAXED, __HIP_MEMORY_SCOPE_AGENT);
        __hip_atomic_store(&slot[3], t3, __ATOMIC_RELAXED, __HIP_MEMORY_SCOPE_AGENT);
        // ensure the 4 stores are committed before the ticket increment
        asm volatile("s_waitcnt vmcnt(0)" ::: "memory");
        const unsigned prev = __hip_atomic_fetch_add(ticket, 1u,
                                __ATOMIC_RELAXED, __HIP_MEMORY_SCOPE_AGENT);
        sIsLast = (prev == (unsigned)(nblocks - 1)) ? 1 : 0;
    }
    __syncthreads();
    if (sIsLast == 0) return;

    // ---------------- last block: per-image normalize + final reduce -------
    float obj = 0.f, cls = 0.f, box = 0.f, np = 0.f;
    for (int bb = tid; bb < B; bb += BLOCK) {
        float bs = 0.f, ps = 0.f, os = 0.f, cs = 0.f;
        const float* s = acc + (size_t)bb * NBY * 4;
        #pragma unroll
        for (int j = 0; j < NBY; ++j) {
            bs += __hip_atomic_load(&s[j * 4 + 0], __ATOMIC_RELAXED, __HIP_MEMORY_SCOPE_AGENT);
            ps += __hip_atomic_load(&s[j * 4 + 1], __ATOMIC_RELAXED, __HIP_MEMORY_SCOPE_AGENT);
            os += __hip_atomic_load(&s[j * 4 + 2], __ATOMIC_RELAXED, __HIP_MEMORY_SCOPE_AGENT);
            cs += __hip_atomic_load(&s[j * 4 + 3], __ATOMIC_RELAXED, __HIP_MEMORY_SCOPE_AGENT);
        }
        obj += os * (1.0f / (float)ATOT);
        const float denom = fmaxf(ps, 1.0f);
        cls += (ps > 0.f) ? cs / (denom * (float)NUM_CLASSES) : 0.f;
        box += (ps > 0.f) ? bs / denom : 0.f;
        np  += ps;
    }
    float u0 = obj, u1 = cls, u2 = box, u3 = np;
    for (int off = 32; off > 0; off >>= 1) {
        u0 += __shfl_down(u0, off, 64);
        u1 += __shfl_down(u1, off, 64);
        u2 += __shfl_down(u2, off, 64);
        u3 += __shfl_down(u3, off, 64);
    }
    __shared__ float sfin[NWAVE][4];
    if (lane == 0) {
        sfin[wave][0] = u0; sfin[wave][1] = u1;
        sfin[wave][2] = u2; sfin[wave][3] = u3;
    }
    __syncthreads();
    if (tid == 0) {
        float t0 = 0.f, t1 = 0.f, t2 = 0.f, t3 = 0.f;
        #pragma unroll
        for (int w = 0; w < NWAVE; ++w) {
            t0 += sfin[w][0]; t1 += sfin[w][1];
            t2 += sfin[w][2]; t3 += sfin[w][3];
        }
        out[0] = 5.0f * t2 + t0 + t1;  // total
        out[1] = t2;
        out[2] = t0;
        out[3] = t1;
        out[4] = t3;
    }
}

extern "C" void kernel_launch(void* const* d_in, const int* in_sizes, int n_in,
                              void* d_out, int out_size, void* d_ws, size_t ws_size,
                              hipStream_t stream) {
    const float* pred = (const float*)d_in[0];
    const float* tgt  = (const float*)d_in[1];
    const int*   isz  = (const int*)d_in[2];
    float* out = (float*)d_out;

    const int B = in_sizes[1] / (MT * 5);

    // ws layout: acc [B*NBY*4] floats, then ticket [1] unsigned
    float*    acc    = (float*)d_ws;
    unsigned* ticket = (unsigned*)(acc + (size_t)B * NBY * 4);

    hipMemsetAsync(ticket, 0, sizeof(unsigned), stream);

    dim3 grid(NBY, B);
    yolox_fused<<<grid, BLOCK, 0, stream>>>(pred, tgt, isz, acc, ticket, out,
                                            B, NBY * B);
}

// Round 6
// 261.192 us; speedup vs baseline: 1.3491x; 1.0283x over previous
//
#include <hip/hip_runtime.h>
#include <math.h>

#define NUM_CLASSES 80
#define MT 50              // max targets per image
#define ATOT 8400          // 80*80 + 40*40 + 20*20
#define CH 85              // 5 + NUM_CLASSES
#define EPI (ATOT * CH)    // 714000 floats per image
#define BLOCK 256
#define CHUNK 256          // anchors per block
#define NBY 33             // ceil(ATOT / CHUNK)
#define NWAVE (BLOCK / 64)

__device__ __forceinline__ float softplus_fast(float x) {
    // stable softplus via HW transcendentals: max(x,0) + log(1 + exp(-|x|))
    return fmaxf(x, 0.0f) + __logf(1.0f + __expf(-fabsf(x)));
}

// ---------------- Fused kernel: match + IoU + obj + compacted cls ----------
// One block owns 256 consecutive anchors of one image.
// Phase 1 (anchor-per-thread): nearest-target match (targets compacted in
//   LDS), obj BCE for ALL anchors (reads p[a*85+4]), box IoU for positives.
//   Positives are ballot-compacted into an LDS list.
// Phase 2: dense class sweep over npos*80 elements from the compacted list —
//   no dead iterations, no per-group mod-85 decode, coalesced scalar loads.
// NOTE (R4/R5 lesson): keep stage2 as a separate tiny kernel. The in-kernel
//   last-block-done ticket was tried twice: __threadfence() variant cost
//   +90 µs (per-block buffer_wbl2/inv L2 flushes); AGENT-scope atomic
//   variant was still +7 µs net (memset dispatch + uncached tail). The
//   two-kernel form is the measured best (261.5 µs).
__global__ __launch_bounds__(BLOCK) void yolox_fused(
        const float* __restrict__ pred,   // [B, ATOT, CH]
        const float* __restrict__ tgt,    // [B, MT, 5]
        const int*   __restrict__ isz,
        float* __restrict__ acc) {        // [B, NBY, 4]  box, np, obj, cls
    const int b  = blockIdx.y;
    const int by = blockIdx.x;
    const int a0 = by * CHUNK;
    const int nanch = min(CHUNK, ATOT - a0);
    const int tid = threadIdx.x;

    __shared__ float2 sxy[64];
    __shared__ float2 swh[64];
    __shared__ float  scls[64];
    __shared__ int    snv;
    __shared__ int    swcnt[NWAVE];       // per-wave positive counts
    __shared__ int    splist[CHUNK];      // (cls<<8)|a_local for positives

    // wave-0 ballot compaction of valid targets (order-preserving)
    if (tid < 64) {
        const int m = tid;
        const float fsize = (float)(*isz);
        float c = -1.0f, x = 0.f, y = 0.f, w = 0.f, h = 0.f;
        if (m < MT) {
            const float* tb = tgt + (size_t)b * MT * 5 + (size_t)m * 5;
            c = tb[0];
            x = tb[1] * fsize; y = tb[2] * fsize;
            w = tb[3] * fsize; h = tb[4] * fsize;
        }
        const bool valid = (m < MT) && (c >= 0.0f);
        const unsigned long long ballot = __ballot(valid);
        const int slot = __popcll(ballot & ((1ull << tid) - 1ull));
        if (valid) {
            sxy[slot]  = make_float2(x, y);
            swh[slot]  = make_float2(w, h);
            scls[slot] = c;
        }
        if (m == 0) snv = (int)__popcll(ballot);
    }
    __syncthreads();
    const int nv = snv;

    const float* pblock = pred + (size_t)b * EPI + (size_t)a0 * CH;

    float box_s = 0.f, np_s = 0.f, obj_s = 0.f;
    int myCls = -1;

    if (tid < nanch) {
        const int a = a0 + tid;
        // anchor geometry, compile-time divisors (magic-mul)
        float ax, ay;
        if (a < 6400)      { const int yy = a / 80;              const int xx = a - yy * 80;  ax = (float)(xx * 8  + 4);  ay = (float)(yy * 8  + 4); }
        else if (a < 8000) { const int i2 = a - 6400; const int yy = i2 / 40; const int xx = i2 - yy * 40; ax = (float)(xx * 16 + 8);  ay = (float)(yy * 16 + 8); }
        else               { const int i2 = a - 8000; const int yy = i2 / 20; const int xx = i2 - yy * 20; ax = (float)(xx * 32 + 16); ay = (float)(yy * 32 + 16); }

        float best = INFINITY;
        int bestm = 0;
        for (int m = 0; m < nv; ++m) {
            const float2 g = sxy[m];
            const float dx = g.x - ax, dy = g.y - ay;
            const float d2 = dx * dx + dy * dy;
            if (d2 < best) { best = d2; bestm = m; }
        }
        const bool pos = best < 4096.0f;  // 64^2

        const float* p = pblock + tid * CH;
        // obj BCE for every anchor: softplus(x) - t*x, t = pos
        const float xo = p[4];
        obj_s = softplus_fast(xo) - (pos ? xo : 0.0f);

        if (pos) {
            myCls = (int)scls[bestm];
            np_s  = 1.0f;
            const float pcx = p[0], pcy = p[1];
            const float pw = __expf(p[2]), ph = __expf(p[3]);
            const float2 g  = sxy[bestm];
            const float2 wh = swh[bestm];
            const float p1x = pcx - pw * 0.5f, p2x = pcx + pw * 0.5f;
            const float p1y = pcy - ph * 0.5f, p2y = pcy + ph * 0.5f;
            const float t1x = g.x - wh.x * 0.5f, t2x = g.x + wh.x * 0.5f;
            const float t1y = g.y - wh.y * 0.5f, t2y = g.y + wh.y * 0.5f;
            const float iw = fminf(p2x, t2x) - fmaxf(p1x, t1x);
            const float ih = fminf(p2y, t2y) - fmaxf(p1y, t1y);
            const float inter = fmaxf(iw, 0.f) * fmaxf(ih, 0.f);
            const float pa = (p2x - p1x) * (p2y - p1y);
            const float ta = (t2x - t1x) * (t2y - t1y);
            const float uni = pa + ta - inter;
            box_s = 1.0f - inter / (uni + 1e-6f);
        }
    }

    // ---------------- block-wide compaction of positive anchors ------------
    const bool isPos = (myCls >= 0);
    const unsigned long long bal = __ballot(isPos);
    const int wave = tid >> 6;
    const int lane = tid & 63;
    if (lane == 0) swcnt[wave] = (int)__popcll(bal);
    __syncthreads();
    int woff = 0, npos = 0;
    #pragma unroll
    for (int w = 0; w < NWAVE; ++w) {
        const int c = swcnt[w];
        if (w < wave) woff += c;
        npos += c;
    }
    if (isPos) {
        const int slot = woff + (int)__popcll(bal & ((1ull << lane) - 1ull));
        splist[slot] = (myCls << 8) | tid;
    }
    __syncthreads();

    // ---------------- Phase 2: dense class sweep over positives ------------
    float cls_s = 0.f;
    const int total = npos * NUM_CLASSES;

    int i = tid;
    for (; i + 3 * BLOCK < total; i += 4 * BLOCK) {
        int   off[4], cc[4], mm[4];
        #pragma unroll
        for (int k = 0; k < 4; ++k) {
            const unsigned ii = (unsigned)(i + k * BLOCK);
            const unsigned pi = ii / NUM_CLASSES;          // compile-time magic
            const int c  = (int)(ii - pi * NUM_CLASSES);
            const int pk = splist[pi];
            const int a  = pk & 0xFF;
            cc[k]  = c;
            mm[k]  = pk >> 8;
            off[k] = a * CH + 5 + c;
        }
        float x[4];
        #pragma unroll
        for (int k = 0; k < 4; ++k) x[k] = pblock[off[k]];
        #pragma unroll
        for (int k = 0; k < 4; ++k)
            cls_s += softplus_fast(x[k]) - ((cc[k] == mm[k]) ? x[k] : 0.0f);
    }
    for (; i < total; i += BLOCK) {
        const unsigned ii = (unsigned)i;
        const unsigned pi = ii / NUM_CLASSES;
        const int c  = (int)(ii - pi * NUM_CLASSES);
        const int pk = splist[pi];
        const int a  = pk & 0xFF;
        const int m  = pk >> 8;
        const float x = pblock[a * CH + 5 + c];
        cls_s += softplus_fast(x) - ((c == m) ? x : 0.0f);
    }

    // ---------------- block reduction of (box, np, obj, cls) ---------------
    float v0 = box_s, v1 = np_s, v2 = obj_s, v3 = cls_s;
    for (int off2 = 32; off2 > 0; off2 >>= 1) {
        v0 += __shfl_down(v0, off2, 64);
        v1 += __shfl_down(v1, off2, 64);
        v2 += __shfl_down(v2, off2, 64);
        v3 += __shfl_down(v3, off2, 64);
    }
    __shared__ float sred[NWAVE][4];
    if (lane == 0) {
        sred[wave][0] = v0; sred[wave][1] = v1;
        sred[wave][2] = v2; sred[wave][3] = v3;
    }
    __syncthreads();
    if (tid == 0) {
        float t0 = 0.f, t1 = 0.f, t2 = 0.f, t3 = 0.f;
        #pragma unroll
        for (int w = 0; w < NWAVE; ++w) {
            t0 += sred[w][0]; t1 += sred[w][1];
            t2 += sred[w][2]; t3 += sred[w][3];
        }
        float* slot = acc + ((size_t)b * NBY + by) * 4;
        slot[0] = t0; slot[1] = t1; slot[2] = t2; slot[3] = t3;
    }
}

// ---------------- Stage 2: per-image normalize + final reduce ---------------
__global__ __launch_bounds__(BLOCK) void yolox_stage2(
        const float* __restrict__ acc,    // [B, NBY, 4] box, np, obj, cls
        float* __restrict__ out, int B) {
    float obj = 0.f, cls = 0.f, box = 0.f, np = 0.f;
    for (int bb = threadIdx.x; bb < B; bb += BLOCK) {
        float bs = 0.f, ps = 0.f, os = 0.f, cs = 0.f;
        const float* s = acc + (size_t)bb * NBY * 4;
        #pragma unroll
        for (int j = 0; j < NBY; ++j) {
            bs += s[j * 4 + 0]; ps += s[j * 4 + 1];
            os += s[j * 4 + 2]; cs += s[j * 4 + 3];
        }
        obj += os * (1.0f / (float)ATOT);
        const float denom = fmaxf(ps, 1.0f);
        cls += (ps > 0.f) ? cs / (denom * (float)NUM_CLASSES) : 0.f;
        box += (ps > 0.f) ? bs / denom : 0.f;
        np  += ps;
    }
    float v0 = obj, v1 = cls, v2 = box, v3 = np;
    for (int off = 32; off > 0; off >>= 1) {
        v0 += __shfl_down(v0, off, 64);
        v1 += __shfl_down(v1, off, 64);
        v2 += __shfl_down(v2, off, 64);
        v3 += __shfl_down(v3, off, 64);
    }
    __shared__ float sred[BLOCK / 64][4];
    const int wave = threadIdx.x >> 6;
    const int lane = threadIdx.x & 63;
    if (lane == 0) {
        sred[wave][0] = v0; sred[wave][1] = v1;
        sred[wave][2] = v2; sred[wave][3] = v3;
    }
    __syncthreads();
    if (threadIdx.x == 0) {
        float t0 = 0.f, t1 = 0.f, t2 = 0.f, t3 = 0.f;
        #pragma unroll
        for (int w = 0; w < BLOCK / 64; ++w) {
            t0 += sred[w][0]; t1 += sred[w][1];
            t2 += sred[w][2]; t3 += sred[w][3];
        }
        out[0] = 5.0f * t2 + t0 + t1;  // total
        out[1] = t2;
        out[2] = t0;
        out[3] = t1;
        out[4] = t3;
    }
}

extern "C" void kernel_launch(void* const* d_in, const int* in_sizes, int n_in,
                              void* d_out, int out_size, void* d_ws, size_t ws_size,
                              hipStream_t stream) {
    const float* pred = (const float*)d_in[0];
    const float* tgt  = (const float*)d_in[1];
    const int*   isz  = (const int*)d_in[2];
    float* out = (float*)d_out;

    const int B = in_sizes[1] / (MT * 5);

    // ws layout: acc [B*NBY*4] floats
    float* acc = (float*)d_ws;

    dim3 grid(NBY, B);
    yolox_fused<<<grid, BLOCK, 0, stream>>>(pred, tgt, isz, acc);

    yolox_stage2<<<1, BLOCK, 0, stream>>>(acc, out, B);
}